// Round 5
// baseline (309.812 us; speedup 1.0000x reference)
//
#include <hip/hip_runtime.h>
#include <hip/hip_bf16.h>

// ---------------------------------------------------------------------------
// Fused pipeline (R14): R13 (MFMA conv2) with the bank-conflict fix.
//   R13 post-mortem: s_p1h row stride 64 halves = 128 B = 32 banks exactly ->
//   bank index independent of row -> A-frag ds_read_b64 ~8-way conflicts
//   (SQ_LDS_BANK_CONFLICT 1.0M -> 7.2M), LDS pipe serialization, VALUBusy 50%.
//   Fix: stride 72 halves (144 B = 36 dwords): bank depends on py and ky again
//   (~4-way max, the floor for 8B-aligned b64). Frag packing via
//   __builtin_shufflevector (ds_read2_b64, no VALU repack).
//   LDS/block ~31.7KB -> 5 blocks/CU: __launch_bounds__(256,5).
// Overlap scheme unchanged from R12: per-conv-block flags, relaxed agent-scope
// ops only, zero atomics, timestep-major conv ordering.
// ---------------------------------------------------------------------------

#define B_      1024
#define L_      30
#define H_      64
#define NGRUBLK 64
#define P1STR   72          // s_p1h row stride in halves (144 B)

typedef _Float16 half_t;
typedef __attribute__((ext_vector_type(2))) _Float16 half2_t;
typedef __attribute__((ext_vector_type(4))) _Float16 half4;
typedef __attribute__((ext_vector_type(8))) _Float16 half8;
typedef __attribute__((ext_vector_type(4))) float f32x4;

#define MFMA16(A, B, C) __builtin_amdgcn_mfma_f32_16x16x32_f16(A, B, C, 0, 0, 0)

__device__ __forceinline__ float sigmoid_f(float v) {
    return __builtin_amdgcn_rcpf(1.f + __expf(-v));
}
__device__ __forceinline__ float tanh_f(float v) {
    v = fminf(fmaxf(v, -15.f), 15.f);
    const float e = __expf(2.f * v);
    return (e - 1.f) * __builtin_amdgcn_rcpf(e + 1.f);
}
__device__ __forceinline__ void load4_lds(float* r, const float* p) {
    float2 a = *(const float2*)p;
    float2 b = *(const float2*)(p + 2);
    r[0] = a.x; r[1] = a.y; r[2] = b.x; r[3] = b.y;
}

// conv sub-image LDS: 4096 + 2160 + 1440 + 240 = 7936 B
struct alignas(16) ConvSub {
    union {
        float  s_img[32 * 32];   // phase 0/1 input image (f32)
        half_t c2h[2048];        // phase 2 output: [oc][13][14] halves (1820 used)
    } u;
    half_t s_p1h[15 * P1STR];    // conv1 pooled out, [y][x*4+ic], stride 72
    float  s_p2[360];            // pooled conv2 (fc layout c*36+y*6+x)
    float  s_red[60];
};

union alignas(16) SharedU {
    struct {
        half_t hbuf[2][16][72];   // [parity][batch][unit], rows padded 64->72
        half_t xenc[16][40];      // current-step x, cols 0..8 live, rest zero
        half_t xdec[16][40];      // decoder x,    cols 0..3 live, rest zero
    } g;
    ConvSub c[4];
};

__global__ __launch_bounds__(256, 5) void fused_kernel(
    const float* __restrict__ bbox,
    const float* __restrict__ head,
    const float* __restrict__ c1w, const float* __restrict__ c1b,
    const float* __restrict__ c2w, const float* __restrict__ c2b,
    const float* __restrict__ fcw, const float* __restrict__ fcb,
    const float* __restrict__ ewih, const float* __restrict__ ewhh,
    const float* __restrict__ ebih, const float* __restrict__ ebhh,
    const float* __restrict__ dwih, const float* __restrict__ dwhh,
    const float* __restrict__ dbih, const float* __restrict__ dbhh,
    const float* __restrict__ linw, const float* __restrict__ linb,
    float* __restrict__ enc_in,     // [1024][30][9] in d_ws
    unsigned*            flags,     // [7680] in d_ws, pre-zeroed via memset
    float* __restrict__ out)        // [1024][20][4]
{
    __shared__ SharedU su;
    const int tid = threadIdx.x;

    if (blockIdx.x >= NGRUBLK) {
        // ===================== conv role (4 images / block) =================
        const int cb   = (int)blockIdx.x - NGRUBLK;   // conv block 0..7679
        const int sub  = tid >> 6;
        const int lane = tid & 63;
        const int img  = (cb << 2) | sub;
        const int ts   = img >> 10;       // timestep-major ordering
        const int b    = img & 1023;
        auto& S = su.c[sub];

        // ---- conv2 MFMA B-fragments (zeros encode all padding) -------------
        const int oc = lane & 15;         // output channel (10 real)
        const int q  = lane >> 4;         // quad
        half8 B1, B2;                     // k-chunks 0..31 / 32..63
        #pragma unroll
        for (int j = 0; j < 8; ++j) {
            const int slot = ((q & 1) << 3) | j;   // (kx,ic) slot 0..15
            const int kx = slot >> 2, ic = slot & 3;
            const int ky1 = q >> 1;                // chunk1: ky = 0 or 1
            B1[j] = (oc < 10 && kx < 3)
                  ? (half_t)c2w[oc * 36 + ic * 9 + ky1 * 3 + kx] : (half_t)0.f;
            B2[j] = (oc < 10 && kx < 3 && q < 2)   // chunk2: ky=2 (k<48), rest 0
                  ? (half_t)c2w[oc * 36 + ic * 9 + 6 + kx] : (half_t)0.f;
        }
        const float bc2 = (oc < 10) ? c2b[oc] : 0.f;

        {
            const float4* src = (const float4*)(head + ((size_t)b * 31 + (size_t)ts) * 1024);
            float4* dstv = (float4*)S.u.s_img;
            #pragma unroll
            for (int i = 0; i < 4; ++i) dstv[lane + 64 * i] = src[lane + 64 * i];
        }
        __syncthreads();

        // ---- conv1 + pool (scalar, unchanged math; f16 interleaved store) --
        if (lane < 60) {
            const int c = lane / 15, px = lane % 15;
            const int x0 = 2 * px;
            float wg[9];
            #pragma unroll
            for (int k = 0; k < 9; ++k) wg[k] = c1w[c * 9 + k];
            const float bias = c1b[c];

            auto c1out = [&](const float* ra, const float* rb, const float* rc, const float* rd) -> float {
                float a00 = bias, a01 = bias, a10 = bias, a11 = bias;
                #pragma unroll
                for (int kx = 0; kx < 3; ++kx) {
                    const float w0 = wg[kx], w1 = wg[3 + kx], w2 = wg[6 + kx];
                    a00 = fmaf(w0, ra[kx],     fmaf(w1, rb[kx],     fmaf(w2, rc[kx],     a00)));
                    a01 = fmaf(w0, ra[kx + 1], fmaf(w1, rb[kx + 1], fmaf(w2, rc[kx + 1], a01)));
                    a10 = fmaf(w0, rb[kx],     fmaf(w1, rc[kx],     fmaf(w2, rd[kx],     a10)));
                    a11 = fmaf(w0, rb[kx + 1], fmaf(w1, rc[kx + 1], fmaf(w2, rd[kx + 1], a11)));
                }
                a00 = fmaxf(a00, 0.f); a01 = fmaxf(a01, 0.f);
                a10 = fmaxf(a10, 0.f); a11 = fmaxf(a11, 0.f);
                return fmaxf(fmaxf(a00, a01), fmaxf(a10, a11));
            };

            float r[6][4];
            load4_lds(r[0], S.u.s_img + 0 * 32 + x0);
            load4_lds(r[1], S.u.s_img + 1 * 32 + x0);
            #pragma unroll
            for (int i = 0; i < 7; ++i) {
                const int s0 = (4 * i) % 6, s1 = (4 * i + 1) % 6, s2 = (4 * i + 2) % 6;
                const int s3 = (4 * i + 3) % 6, s4 = (4 * i + 4) % 6, s5 = (4 * i + 5) % 6;
                load4_lds(r[s2], S.u.s_img + (4 * i + 2) * 32 + x0);
                load4_lds(r[s3], S.u.s_img + (4 * i + 3) * 32 + x0);
                S.s_p1h[(2 * i) * P1STR + px * 4 + c] = (half_t)c1out(r[s0], r[s1], r[s2], r[s3]);
                load4_lds(r[s4], S.u.s_img + (4 * i + 4) * 32 + x0);
                load4_lds(r[s5], S.u.s_img + (4 * i + 5) * 32 + x0);
                S.s_p1h[(2 * i + 1) * P1STR + px * 4 + c] = (half_t)c1out(r[s2], r[s3], r[s4], r[s5]);
            }
            load4_lds(r[0], S.u.s_img + 30 * 32 + x0);
            load4_lds(r[1], S.u.s_img + 31 * 32 + x0);
            S.s_p1h[14 * P1STR + px * 4 + c] = (half_t)c1out(r[4], r[5], r[0], r[1]);

            // zero pad cols 60..63 of all 15 rows (A-frags read into them;
            // must be finite since B=0 slots still do 0*x)
            S.s_p1h[(lane % 15) * P1STR + 60 + lane / 15] = (half_t)0.f;
        }
        __syncthreads();

        // ---- conv2 via MFMA implicit GEMM: 11 M-tiles x 2 MFMA -------------
        {
            const int m = lane & 15;
            const int off = (q & 1) << 3;
            #pragma unroll
            for (int t2 = 0; t2 < 11; ++t2) {
                const int pm0 = t2 * 16 + m;
                const int pm  = pm0 > 168 ? 168 : pm0;   // clamp tail (discarded)
                const int py  = (pm * 79) >> 10;         // /13 (exact for 0..175)
                const int px  = pm - py * 13;
                const int base1 = (py + (q >> 1)) * P1STR + px * 4 + off;  // ky=q>>1
                const int base2 = (py + 2) * P1STR + px * 4 + off;         // ky=2
                const half4 a1lo = *(const half4*)&S.s_p1h[base1];
                const half4 a1hi = *(const half4*)&S.s_p1h[base1 + 4];
                const half4 a2lo = *(const half4*)&S.s_p1h[base2];
                const half4 a2hi = *(const half4*)&S.s_p1h[base2 + 4];
                const half8 a1 = __builtin_shufflevector(a1lo, a1hi, 0,1,2,3,4,5,6,7);
                const half8 a2 = __builtin_shufflevector(a2lo, a2hi, 0,1,2,3,4,5,6,7);
                f32x4 Cc = {bc2, bc2, bc2, bc2};
                Cc = MFMA16(a1, B1, Cc);
                Cc = MFMA16(a2, B2, Cc);

                if (oc < 10) {
                    #pragma unroll
                    for (int r2 = 0; r2 < 4; ++r2) {
                        const int p = t2 * 16 + q * 4 + r2;
                        if (p < 169) {
                            const int wy = (p * 79) >> 10;
                            const int wx = p - wy * 13;
                            S.u.c2h[oc * 182 + wy * 14 + wx] =
                                (half_t)fmaxf(Cc[r2], 0.f);
                        }
                    }
                }
            }
        }
        __syncthreads();

        // ---- 2x2 maxpool 13x13 -> 6x6, f32 store in fc layout --------------
        if (lane < 60) {
            const int c = lane / 6, x = lane % 6;
            const half_t* cbase = &S.u.c2h[c * 182 + 2 * x];
            float* dstp = &S.s_p2[c * 36 + x];
            #pragma unroll
            for (int y = 0; y < 6; ++y) {
                const half2_t ha = *(const half2_t*)(cbase + (2 * y) * 14);
                const half2_t hb = *(const half2_t*)(cbase + (2 * y + 1) * 14);
                dstp[y * 6] = fmaxf(fmaxf((float)ha[0], (float)ha[1]),
                                    fmaxf((float)hb[0], (float)hb[1]));
            }
        }
        __syncthreads();

        // ---- fc partials ---------------------------------------------------
        if (lane < 60) {
            const int o = lane / 12, i0 = lane % 12;
            const float* wrow = fcw + o * 360;
            float acc = 0.f;
            #pragma unroll
            for (int k = 0; k < 30; ++k) {
                const int i = i0 + 12 * k;
                acc = fmaf(wrow[i], S.s_p2[i], acc);
            }
            S.s_red[lane] = acc;
        }
        __syncthreads();

        // publish via agent-scope RELAXED stores (bypass non-coherent caches,
        // complete at the coherent point).
        float* dst = enc_in + ((size_t)b * L_ + ts) * 9;
        if (lane < 5) {
            float acc = fcb[lane];
            #pragma unroll
            for (int k = 0; k < 12; ++k) acc += S.s_red[lane * 12 + k];
            __hip_atomic_store(&dst[4 + lane], acc, __ATOMIC_RELAXED, __HIP_MEMORY_SCOPE_AGENT);
        } else if (lane >= 8 && lane < 12) {
            const int d = lane - 8;
            const float* bbp = bbox + (size_t)b * 124 + (size_t)ts * 4;
            __hip_atomic_store(&dst[d], bbp[4 + d] - bbp[d], __ATOMIC_RELAXED, __HIP_MEMORY_SCOPE_AGENT);
        }
        __syncthreads();   // drains vmcnt -> all 4 sub-images' stores complete
        // one private flag store per block — no shared lines, no atomics
        if (tid == 0)
            __hip_atomic_store(&flags[cb], 1u, __ATOMIC_RELAXED, __HIP_MEMORY_SCOPE_AGENT);
        return;
    }

    // ======================= GRU role (blocks 0..63) ========================
    const int g   = (int)blockIdx.x;        // GRU block id
    const int bb  = g * 16;                 // first batch of this block
    const int w   = tid >> 6;               // wave 0..3
    const int l   = tid & 63;
    const int q   = l >> 4;                 // quad 0..3
    const int col = l & 15;
    auto& G = su.g;

    // ---- zero LDS (7168 B = 448 int4) --------------------------------------
    {
        int4* p = (int4*)&G;
        #pragma unroll
        for (int i = 0; i < 2; ++i) {
            const int idx = tid + 256 * i;
            if (idx < (int)(sizeof(G) / 16)) p[idx] = int4{0, 0, 0, 0};
        }
    }

    // ---- weight B-fragments (register-resident, f16) -----------------------
    const int urow = 16 * w + col;
    auto whh_frag = [&](const float* W, int gate, int kap) -> half8 {
        const float* rp = W + (size_t)(gate * 64 + urow) * 64 + kap * 32 + q * 8;
        half8 f;
        #pragma unroll
        for (int j = 0; j < 8; ++j) f[j] = (half_t)rp[j];
        return f;
    };
    auto wih_frag = [&](const float* W, int gate, int indim) -> half8 {
        half8 f;
        #pragma unroll
        for (int j = 0; j < 8; ++j) {
            const int d = q * 8 + j;
            f[j] = (d < indim) ? (half_t)W[(size_t)(gate * 64 + urow) * indim + d]
                               : (half_t)0.f;
        }
        return f;
    };

    // encoder frags only (decoder frags loaded after the encoder loop to keep
    // peak VGPR under the __launch_bounds__ cap)
    const half8 eBr0 = whh_frag(ewhh, 0, 0), eBr1 = whh_frag(ewhh, 0, 1);
    const half8 eBz0 = whh_frag(ewhh, 1, 0), eBz1 = whh_frag(ewhh, 1, 1);
    const half8 eBn0 = whh_frag(ewhh, 2, 0), eBn1 = whh_frag(ewhh, 2, 1);
    const half8 eBrx = wih_frag(ewih, 0, 9);
    const half8 eBzx = wih_frag(ewih, 1, 9);
    const half8 eBnx = wih_frag(ewih, 2, 9);

    const float ebr  = ebih[urow]       + ebhh[urow];
    const float ebz  = ebih[64 + urow]  + ebhh[64 + urow];
    const float ebnh = ebhh[128 + urow];
    const float ebni = ebih[128 + urow];

    float hold[4] = {0.f, 0.f, 0.f, 0.f};
    __syncthreads();   // LDS zeros visible

    // =================== encoder: 30 steps, paced by conv ==================
    for (int t = 0; t < L_; ++t) {
        // wait only for the 4 conv blocks that produce batches bb..bb+15 at t
        if (tid < 4) {
            const unsigned fidx = (unsigned)(t * 256 + 4 * g + tid);
            while (__hip_atomic_load(&flags[fidx], __ATOMIC_RELAXED,
                                     __HIP_MEMORY_SCOPE_AGENT) == 0u)
                __builtin_amdgcn_s_sleep(2);
        }
        __syncthreads();
        if (tid < 144) {   // stage 16 batches x 9 dims for this step
            const int bq = tid / 9, d = tid - 9 * bq;
            const float v = __hip_atomic_load(
                &enc_in[((size_t)(bb + bq) * L_ + t) * 9 + d],
                __ATOMIC_RELAXED, __HIP_MEMORY_SCOPE_AGENT);
            G.xenc[bq][d] = (half_t)v;
        }
        __syncthreads();

        const int p = t & 1;
        const half8 a0 = *(const half8*)&G.hbuf[p][col][q * 8];        // k 0..31
        const half8 a1 = *(const half8*)&G.hbuf[p][col][32 + q * 8];   // k 32..63
        const half8 a2 = *(const half8*)&G.xenc[col][q * 8];           // k 64..95

        f32x4 Cr  = {ebr, ebr, ebr, ebr};
        f32x4 Cz  = {ebz, ebz, ebz, ebz};
        f32x4 Cnh = {ebnh, ebnh, ebnh, ebnh};
        f32x4 Cnx = {ebni, ebni, ebni, ebni};
        Cr  = MFMA16(a0, eBr0, Cr);  Cr  = MFMA16(a1, eBr1, Cr);  Cr = MFMA16(a2, eBrx, Cr);
        Cz  = MFMA16(a0, eBz0, Cz);  Cz  = MFMA16(a1, eBz1, Cz);  Cz = MFMA16(a2, eBzx, Cz);
        Cnh = MFMA16(a0, eBn0, Cnh); Cnh = MFMA16(a1, eBn1, Cnh);
        Cnx = MFMA16(a2, eBnx, Cnx);

        #pragma unroll
        for (int r = 0; r < 4; ++r) {
            const float rr = sigmoid_f(Cr[r]);
            const float zz = sigmoid_f(Cz[r]);
            const float nn = tanh_f(Cnx[r] + rr * Cnh[r]);
            hold[r] = fmaf(zz, hold[r] - nn, nn);
            G.hbuf[p ^ 1][q * 4 + r][urow] = (half_t)hold[r];
        }
        __syncthreads();
    }

    // ---- decoder weights / lin head / x0 (loaded after encoder) ------------
    const half8 dBr0 = whh_frag(dwhh, 0, 0), dBr1 = whh_frag(dwhh, 0, 1);
    const half8 dBz0 = whh_frag(dwhh, 1, 0), dBz1 = whh_frag(dwhh, 1, 1);
    const half8 dBn0 = whh_frag(dwhh, 2, 0), dBn1 = whh_frag(dwhh, 2, 1);
    const half8 dBrx = wih_frag(dwih, 0, 4);
    const half8 dBzx = wih_frag(dwih, 1, 4);
    const half8 dBnx = wih_frag(dwih, 2, 4);

    half8 Bl0, Bl1;
    #pragma unroll
    for (int j = 0; j < 8; ++j) {
        Bl0[j] = (col < 4) ? (half_t)linw[col * 64 +      q * 8 + j] : (half_t)0.f;
        Bl1[j] = (col < 4) ? (half_t)linw[col * 64 + 32 + q * 8 + j] : (half_t)0.f;
    }

    const float dbr  = dbih[urow]       + dbhh[urow];
    const float dbz  = dbih[64 + urow]  + dbhh[64 + urow];
    const float dbnh = dbhh[128 + urow];
    const float dbni = dbih[128 + urow];
    const float lb   = (col < 4) ? linb[col] : 0.f;

    float xold[4], ofs[4], cs[4];
    if (w == 0 && col < 4) {
        #pragma unroll
        for (int r = 0; r < 4; ++r) {
            const float* bbp = bbox + (size_t)(bb + q * 4 + r) * 124;
            xold[r] = bbp[120 + col] - bbp[116 + col];
            ofs[r]  = bbp[120 + col];
            cs[r]   = 0.f;
            G.xdec[q * 4 + r][col] = (half_t)xold[r];
        }
    }
    __syncthreads();   // xdec visible

    // =================== decoder: 20 steps + lin + cumsum ==================
    for (int tt = 0; tt < 20; ++tt) {
        const int p = tt & 1;   // (30+tt)&1 == tt&1
        const half8 a0 = *(const half8*)&G.hbuf[p][col][q * 8];
        const half8 a1 = *(const half8*)&G.hbuf[p][col][32 + q * 8];
        const half8 a2 = *(const half8*)&G.xdec[col][q * 8];

        f32x4 Cr  = {dbr, dbr, dbr, dbr};
        f32x4 Cz  = {dbz, dbz, dbz, dbz};
        f32x4 Cnh = {dbnh, dbnh, dbnh, dbnh};
        f32x4 Cnx = {dbni, dbni, dbni, dbni};
        Cr  = MFMA16(a0, dBr0, Cr);  Cr  = MFMA16(a1, dBr1, Cr);  Cr = MFMA16(a2, dBrx, Cr);
        Cz  = MFMA16(a0, dBz0, Cz);  Cz  = MFMA16(a1, dBz1, Cz);  Cz = MFMA16(a2, dBzx, Cz);
        Cnh = MFMA16(a0, dBn0, Cnh); Cnh = MFMA16(a1, dBn1, Cnh);
        Cnx = MFMA16(a2, dBnx, Cnx);

        #pragma unroll
        for (int r = 0; r < 4; ++r) {
            const float rr = sigmoid_f(Cr[r]);
            const float zz = sigmoid_f(Cz[r]);
            const float nn = tanh_f(Cnx[r] + rr * Cnh[r]);
            hold[r] = fmaf(zz, hold[r] - nn, nn);
            G.hbuf[p ^ 1][q * 4 + r][urow] = (half_t)hold[r];
        }
        __syncthreads();   // (A) h_new visible for lin-head A-frags

        const half8 al0 = *(const half8*)&G.hbuf[p ^ 1][col][q * 8];
        const half8 al1 = *(const half8*)&G.hbuf[p ^ 1][col][32 + q * 8];
        f32x4 X = {0.f, 0.f, 0.f, 0.f};
        X = MFMA16(al0, Bl0, X);
        X = MFMA16(al1, Bl1, X);

        if (w == 0 && col < 4) {
            #pragma unroll
            for (int r = 0; r < 4; ++r) {
                const float xv = X[r] + lb + xold[r];
                xold[r] = xv;
                cs[r] += xv;
                G.xdec[q * 4 + r][col] = (half_t)xv;
                out[(size_t)(bb + q * 4 + r) * 80 + tt * 4 + col] = cs[r] + ofs[r];
            }
        }
        __syncthreads();   // (B) xdec visible for next step's gi
    }
}

// ---------------------------------------------------------------------------
extern "C" void kernel_launch(void* const* d_in, const int* in_sizes, int n_in,
                              void* d_out, int out_size, void* d_ws, size_t ws_size,
                              hipStream_t stream) {
    (void)in_sizes; (void)n_in; (void)out_size; (void)ws_size;
    const float* bbox = (const float*)d_in[0];
    const float* head = (const float*)d_in[1];
    const float* c1w  = (const float*)d_in[2];
    const float* c1b  = (const float*)d_in[3];
    const float* c2w  = (const float*)d_in[4];
    const float* c2b  = (const float*)d_in[5];
    const float* fcw  = (const float*)d_in[6];
    const float* fcb  = (const float*)d_in[7];
    const float* ewih = (const float*)d_in[8];
    const float* ewhh = (const float*)d_in[9];
    const float* ebih = (const float*)d_in[10];
    const float* ebhh = (const float*)d_in[11];
    const float* dwih = (const float*)d_in[12];
    const float* dwhh = (const float*)d_in[13];
    const float* dbih = (const float*)d_in[14];
    const float* dbhh = (const float*)d_in[15];
    const float* linw = (const float*)d_in[16];
    const float* linb = (const float*)d_in[17];
    float* out = (float*)d_out;

    float*    enc_in = (float*)d_ws;                       // 1024*30*9 floats
    unsigned* flags  = (unsigned*)((char*)d_ws + (size_t)B_ * L_ * 9 * sizeof(float));

    // zero 7680 per-conv-block flags each replay (captured in the graph)
    hipMemsetAsync(flags, 0, (B_ * L_ / 4) * sizeof(unsigned), stream);

    const int grid = NGRUBLK + (B_ * L_) / 4;              // 64 gru + 7680 conv
    fused_kernel<<<grid, 256, 0, stream>>>(bbox, head, c1w, c1b, c2w, c2b,
                                           fcw, fcb, ewih, ewhh, ebih, ebhh,
                                           dwih, dwhh, dbih, dbhh, linw, linb,
                                           enc_in, flags, out);
}

// Round 6
// 277.537 us; speedup vs baseline: 1.1163x; 1.1163x over previous
//
#include <hip/hip_runtime.h>
#include <hip/hip_bf16.h>

// ---------------------------------------------------------------------------
// Fused pipeline (R15): REVERT to R12 structure (scalar conv2) per the
// pre-committed R14 decision rule (MFMA conv2 = latency-bound at low VGPR;
// removed VALU replaced by LDS-latency stall, net regression).
// Single change vs R12: __launch_bounds__(256,4). R12's LDS (38912 B) allows
// 4 blocks/CU (155.6KB <= 160KB); R12's (256,3) was needlessly conservative.
// 16 waves/CU (+33% TLP) should lift conv VALU issue from 80% toward ~90%+.
// Overlap scheme unchanged: per-conv-block flags, relaxed agent-scope ops
// only, zero atomics, timestep-major conv ordering.
// ---------------------------------------------------------------------------

#define B_      1024
#define L_      30
#define H_      64
#define NGRUBLK 64

typedef _Float16 half_t;
typedef __attribute__((ext_vector_type(8))) _Float16 half8;
typedef __attribute__((ext_vector_type(4))) float f32x4;

#define MFMA16(A, B, C) __builtin_amdgcn_mfma_f32_16x16x32_f16(A, B, C, 0, 0, 0)

__device__ __forceinline__ float sigmoid_f(float v) {
    return __builtin_amdgcn_rcpf(1.f + __expf(-v));
}
__device__ __forceinline__ float tanh_f(float v) {
    v = fminf(fmaxf(v, -15.f), 15.f);
    const float e = __expf(2.f * v);
    return (e - 1.f) * __builtin_amdgcn_rcpf(e + 1.f);
}
__device__ __forceinline__ void load4_lds(float* r, const float* p) {
    float2 a = *(const float2*)p;
    float2 b = *(const float2*)(p + 2);
    r[0] = a.x; r[1] = a.y; r[2] = b.x; r[3] = b.y;
}

// LDS union: conv role needs 4x9616B = 38464B; GRU role needs 7168B.
union alignas(16) SharedU {
    struct {
        half_t hbuf[2][16][72];   // [parity][batch][unit], rows padded 64->72
        half_t xenc[16][40];      // current-step x, cols 0..8 live, rest zero
        half_t xdec[16][40];      // decoder x,    cols 0..3 live, rest zero
    } g;
    struct {
        float s_img[32 * 32];
        float s_p1[4 * 15 * 16];  // [c][py][px], width padded to 16
        float s_p2[360];
        float s_red[60];
    } c[4];
};

__global__ __launch_bounds__(256, 4) void fused_kernel(
    const float* __restrict__ bbox,
    const float* __restrict__ head,
    const float* __restrict__ c1w, const float* __restrict__ c1b,
    const float* __restrict__ c2w, const float* __restrict__ c2b,
    const float* __restrict__ fcw, const float* __restrict__ fcb,
    const float* __restrict__ ewih, const float* __restrict__ ewhh,
    const float* __restrict__ ebih, const float* __restrict__ ebhh,
    const float* __restrict__ dwih, const float* __restrict__ dwhh,
    const float* __restrict__ dbih, const float* __restrict__ dbhh,
    const float* __restrict__ linw, const float* __restrict__ linb,
    float* __restrict__ enc_in,     // [1024][30][9] in d_ws
    unsigned*            flags,     // [7680] in d_ws, pre-zeroed via memset
    float* __restrict__ out)        // [1024][20][4]
{
    __shared__ SharedU su;
    const int tid = threadIdx.x;

    if (blockIdx.x >= NGRUBLK) {
        // ===================== conv role (4 images / block) =================
        const int cb   = (int)blockIdx.x - NGRUBLK;   // conv block 0..7679
        const int sub  = tid >> 6;
        const int lane = tid & 63;
        const int img  = (cb << 2) | sub;
        const int ts   = img >> 10;       // timestep-major ordering
        const int b    = img & 1023;
        auto& S = su.c[sub];

        {
            const float4* src = (const float4*)(head + ((size_t)b * 31 + (size_t)ts) * 1024);
            float4* dstv = (float4*)S.s_img;
            #pragma unroll
            for (int i = 0; i < 4; ++i) dstv[lane + 64 * i] = src[lane + 64 * i];
        }
        __syncthreads();

        if (lane < 60) {
            const int c = lane / 15, px = lane % 15;
            const int x0 = 2 * px;
            float wg[9];
            #pragma unroll
            for (int k = 0; k < 9; ++k) wg[k] = c1w[c * 9 + k];
            const float bias = c1b[c];

            auto c1out = [&](const float* ra, const float* rb, const float* rc, const float* rd) -> float {
                float a00 = bias, a01 = bias, a10 = bias, a11 = bias;
                #pragma unroll
                for (int kx = 0; kx < 3; ++kx) {
                    const float w0 = wg[kx], w1 = wg[3 + kx], w2 = wg[6 + kx];
                    a00 = fmaf(w0, ra[kx],     fmaf(w1, rb[kx],     fmaf(w2, rc[kx],     a00)));
                    a01 = fmaf(w0, ra[kx + 1], fmaf(w1, rb[kx + 1], fmaf(w2, rc[kx + 1], a01)));
                    a10 = fmaf(w0, rb[kx],     fmaf(w1, rc[kx],     fmaf(w2, rd[kx],     a10)));
                    a11 = fmaf(w0, rb[kx + 1], fmaf(w1, rc[kx + 1], fmaf(w2, rd[kx + 1], a11)));
                }
                a00 = fmaxf(a00, 0.f); a01 = fmaxf(a01, 0.f);
                a10 = fmaxf(a10, 0.f); a11 = fmaxf(a11, 0.f);
                return fmaxf(fmaxf(a00, a01), fmaxf(a10, a11));
            };

            float r[6][4];
            load4_lds(r[0], S.s_img + 0 * 32 + x0);
            load4_lds(r[1], S.s_img + 1 * 32 + x0);
            #pragma unroll
            for (int i = 0; i < 7; ++i) {
                const int s0 = (4 * i) % 6, s1 = (4 * i + 1) % 6, s2 = (4 * i + 2) % 6;
                const int s3 = (4 * i + 3) % 6, s4 = (4 * i + 4) % 6, s5 = (4 * i + 5) % 6;
                load4_lds(r[s2], S.s_img + (4 * i + 2) * 32 + x0);
                load4_lds(r[s3], S.s_img + (4 * i + 3) * 32 + x0);
                S.s_p1[c * 240 + (2 * i) * 16 + px] = c1out(r[s0], r[s1], r[s2], r[s3]);
                load4_lds(r[s4], S.s_img + (4 * i + 4) * 32 + x0);
                load4_lds(r[s5], S.s_img + (4 * i + 5) * 32 + x0);
                S.s_p1[c * 240 + (2 * i + 1) * 16 + px] = c1out(r[s2], r[s3], r[s4], r[s5]);
            }
            load4_lds(r[0], S.s_img + 30 * 32 + x0);
            load4_lds(r[1], S.s_img + 31 * 32 + x0);
            S.s_p1[c * 240 + 14 * 16 + px] = c1out(r[4], r[5], r[0], r[1]);
        }
        __syncthreads();

        if (lane < 60) {
            const int c = lane / 6, px = lane % 6;
            const int x0 = 2 * px;
            float wg2[4][9];
            #pragma unroll
            for (int ic = 0; ic < 4; ++ic)
                #pragma unroll
                for (int k = 0; k < 9; ++k) wg2[ic][k] = c2w[(c * 4 + ic) * 9 + k];
            const float bias2 = c2b[c];

            float P[6][4][4];
            auto c2out = [&](float (*pa)[4], float (*pb)[4], float (*pc)[4], float (*pd)[4]) -> float {
                float a00 = bias2, a01 = bias2, a10 = bias2, a11 = bias2;
                #pragma unroll
                for (int ic = 0; ic < 4; ++ic) {
                    #pragma unroll
                    for (int kx = 0; kx < 3; ++kx) {
                        const float w0 = wg2[ic][kx], w1 = wg2[ic][3 + kx], w2 = wg2[ic][6 + kx];
                        a00 = fmaf(w0, pa[ic][kx],     fmaf(w1, pb[ic][kx],     fmaf(w2, pc[ic][kx],     a00)));
                        a01 = fmaf(w0, pa[ic][kx + 1], fmaf(w1, pb[ic][kx + 1], fmaf(w2, pc[ic][kx + 1], a01)));
                        a10 = fmaf(w0, pb[ic][kx],     fmaf(w1, pc[ic][kx],     fmaf(w2, pd[ic][kx],     a10)));
                        a11 = fmaf(w0, pb[ic][kx + 1], fmaf(w1, pc[ic][kx + 1], fmaf(w2, pd[ic][kx + 1], a11)));
                    }
                }
                a00 = fmaxf(a00, 0.f); a01 = fmaxf(a01, 0.f);
                a10 = fmaxf(a10, 0.f); a11 = fmaxf(a11, 0.f);
                return fmaxf(fmaxf(a00, a01), fmaxf(a10, a11));
            };

            #pragma unroll
            for (int ic = 0; ic < 4; ++ic) {
                load4_lds(P[0][ic], S.s_p1 + ic * 240 + 0 * 16 + x0);
                load4_lds(P[1][ic], S.s_p1 + ic * 240 + 1 * 16 + x0);
            }
            #pragma unroll
            for (int i = 0; i < 3; ++i) {
                const int s0 = (4 * i) % 6, s1 = (4 * i + 1) % 6, s2 = (4 * i + 2) % 6;
                const int s3 = (4 * i + 3) % 6, s4 = (4 * i + 4) % 6, s5 = (4 * i + 5) % 6;
                #pragma unroll
                for (int ic = 0; ic < 4; ++ic) {
                    load4_lds(P[s2][ic], S.s_p1 + ic * 240 + (4 * i + 2) * 16 + x0);
                    load4_lds(P[s3][ic], S.s_p1 + ic * 240 + (4 * i + 3) * 16 + x0);
                }
                S.s_p2[c * 36 + (2 * i) * 6 + px] = c2out(P[s0], P[s1], P[s2], P[s3]);
                #pragma unroll
                for (int ic = 0; ic < 4; ++ic) {
                    load4_lds(P[s4][ic], S.s_p1 + ic * 240 + (4 * i + 4) * 16 + x0);
                    load4_lds(P[s5][ic], S.s_p1 + ic * 240 + (4 * i + 5) * 16 + x0);
                }
                S.s_p2[c * 36 + (2 * i + 1) * 6 + px] = c2out(P[s2], P[s3], P[s4], P[s5]);
            }
        }
        __syncthreads();

        if (lane < 60) {
            const int o = lane / 12, i0 = lane % 12;
            const float* wrow = fcw + o * 360;
            float acc = 0.f;
            #pragma unroll
            for (int k = 0; k < 30; ++k) {
                const int i = i0 + 12 * k;
                acc = fmaf(wrow[i], S.s_p2[i], acc);
            }
            S.s_red[lane] = acc;
        }
        __syncthreads();

        // publish via agent-scope RELAXED stores (bypass non-coherent caches,
        // complete at the coherent point).
        float* dst = enc_in + ((size_t)b * L_ + ts) * 9;
        if (lane < 5) {
            float acc = fcb[lane];
            #pragma unroll
            for (int k = 0; k < 12; ++k) acc += S.s_red[lane * 12 + k];
            __hip_atomic_store(&dst[4 + lane], acc, __ATOMIC_RELAXED, __HIP_MEMORY_SCOPE_AGENT);
        } else if (lane >= 8 && lane < 12) {
            const int d = lane - 8;
            const float* bbp = bbox + (size_t)b * 124 + (size_t)ts * 4;
            __hip_atomic_store(&dst[d], bbp[4 + d] - bbp[d], __ATOMIC_RELAXED, __HIP_MEMORY_SCOPE_AGENT);
        }
        __syncthreads();   // drains vmcnt -> all 4 sub-images' stores complete
        // one private flag store per block — no shared lines, no atomics
        if (tid == 0)
            __hip_atomic_store(&flags[cb], 1u, __ATOMIC_RELAXED, __HIP_MEMORY_SCOPE_AGENT);
        return;
    }

    // ======================= GRU role (blocks 0..63) ========================
    const int g   = (int)blockIdx.x;        // GRU block id
    const int bb  = g * 16;                 // first batch of this block
    const int w   = tid >> 6;               // wave 0..3
    const int l   = tid & 63;
    const int q   = l >> 4;                 // quad 0..3
    const int col = l & 15;
    auto& G = su.g;

    // ---- zero LDS (7168 B = 448 int4) --------------------------------------
    {
        int4* p = (int4*)&G;
        #pragma unroll
        for (int i = 0; i < 2; ++i) {
            const int idx = tid + 256 * i;
            if (idx < (int)(sizeof(G) / 16)) p[idx] = int4{0, 0, 0, 0};
        }
    }

    // ---- weight B-fragments (register-resident, f16) -----------------------
    const int urow = 16 * w + col;
    auto whh_frag = [&](const float* W, int gate, int kap) -> half8 {
        const float* rp = W + (size_t)(gate * 64 + urow) * 64 + kap * 32 + q * 8;
        half8 f;
        #pragma unroll
        for (int j = 0; j < 8; ++j) f[j] = (half_t)rp[j];
        return f;
    };
    auto wih_frag = [&](const float* W, int gate, int indim) -> half8 {
        half8 f;
        #pragma unroll
        for (int j = 0; j < 8; ++j) {
            const int d = q * 8 + j;
            f[j] = (d < indim) ? (half_t)W[(size_t)(gate * 64 + urow) * indim + d]
                               : (half_t)0.f;
        }
        return f;
    };

    // encoder frags only (decoder frags loaded after the encoder loop to keep
    // peak VGPR under the __launch_bounds__ cap)
    const half8 eBr0 = whh_frag(ewhh, 0, 0), eBr1 = whh_frag(ewhh, 0, 1);
    const half8 eBz0 = whh_frag(ewhh, 1, 0), eBz1 = whh_frag(ewhh, 1, 1);
    const half8 eBn0 = whh_frag(ewhh, 2, 0), eBn1 = whh_frag(ewhh, 2, 1);
    const half8 eBrx = wih_frag(ewih, 0, 9);
    const half8 eBzx = wih_frag(ewih, 1, 9);
    const half8 eBnx = wih_frag(ewih, 2, 9);

    const float ebr  = ebih[urow]       + ebhh[urow];
    const float ebz  = ebih[64 + urow]  + ebhh[64 + urow];
    const float ebnh = ebhh[128 + urow];
    const float ebni = ebih[128 + urow];

    float hold[4] = {0.f, 0.f, 0.f, 0.f};
    __syncthreads();   // LDS zeros visible

    // =================== encoder: 30 steps, paced by conv ==================
    for (int t = 0; t < L_; ++t) {
        // wait only for the 4 conv blocks that produce batches bb..bb+15 at t
        if (tid < 4) {
            const unsigned fidx = (unsigned)(t * 256 + 4 * g + tid);
            while (__hip_atomic_load(&flags[fidx], __ATOMIC_RELAXED,
                                     __HIP_MEMORY_SCOPE_AGENT) == 0u)
                __builtin_amdgcn_s_sleep(2);
        }
        __syncthreads();
        if (tid < 144) {   // stage 16 batches x 9 dims for this step
            const int bq = tid / 9, d = tid - 9 * bq;
            const float v = __hip_atomic_load(
                &enc_in[((size_t)(bb + bq) * L_ + t) * 9 + d],
                __ATOMIC_RELAXED, __HIP_MEMORY_SCOPE_AGENT);
            G.xenc[bq][d] = (half_t)v;
        }
        __syncthreads();

        const int p = t & 1;
        const half8 a0 = *(const half8*)&G.hbuf[p][col][q * 8];        // k 0..31
        const half8 a1 = *(const half8*)&G.hbuf[p][col][32 + q * 8];   // k 32..63
        const half8 a2 = *(const half8*)&G.xenc[col][q * 8];           // k 64..95

        f32x4 Cr  = {ebr, ebr, ebr, ebr};
        f32x4 Cz  = {ebz, ebz, ebz, ebz};
        f32x4 Cnh = {ebnh, ebnh, ebnh, ebnh};
        f32x4 Cnx = {ebni, ebni, ebni, ebni};
        Cr  = MFMA16(a0, eBr0, Cr);  Cr  = MFMA16(a1, eBr1, Cr);  Cr = MFMA16(a2, eBrx, Cr);
        Cz  = MFMA16(a0, eBz0, Cz);  Cz  = MFMA16(a1, eBz1, Cz);  Cz = MFMA16(a2, eBzx, Cz);
        Cnh = MFMA16(a0, eBn0, Cnh); Cnh = MFMA16(a1, eBn1, Cnh);
        Cnx = MFMA16(a2, eBnx, Cnx);

        #pragma unroll
        for (int r = 0; r < 4; ++r) {
            const float rr = sigmoid_f(Cr[r]);
            const float zz = sigmoid_f(Cz[r]);
            const float nn = tanh_f(Cnx[r] + rr * Cnh[r]);
            hold[r] = fmaf(zz, hold[r] - nn, nn);
            G.hbuf[p ^ 1][q * 4 + r][urow] = (half_t)hold[r];
        }
        __syncthreads();
    }

    // ---- decoder weights / lin head / x0 (loaded after encoder) ------------
    const half8 dBr0 = whh_frag(dwhh, 0, 0), dBr1 = whh_frag(dwhh, 0, 1);
    const half8 dBz0 = whh_frag(dwhh, 1, 0), dBz1 = whh_frag(dwhh, 1, 1);
    const half8 dBn0 = whh_frag(dwhh, 2, 0), dBn1 = whh_frag(dwhh, 2, 1);
    const half8 dBrx = wih_frag(dwih, 0, 4);
    const half8 dBzx = wih_frag(dwih, 1, 4);
    const half8 dBnx = wih_frag(dwih, 2, 4);

    half8 Bl0, Bl1;
    #pragma unroll
    for (int j = 0; j < 8; ++j) {
        Bl0[j] = (col < 4) ? (half_t)linw[col * 64 +      q * 8 + j] : (half_t)0.f;
        Bl1[j] = (col < 4) ? (half_t)linw[col * 64 + 32 + q * 8 + j] : (half_t)0.f;
    }

    const float dbr  = dbih[urow]       + dbhh[urow];
    const float dbz  = dbih[64 + urow]  + dbhh[64 + urow];
    const float dbnh = dbhh[128 + urow];
    const float dbni = dbih[128 + urow];
    const float lb   = (col < 4) ? linb[col] : 0.f;

    float xold[4], ofs[4], cs[4];
    if (w == 0 && col < 4) {
        #pragma unroll
        for (int r = 0; r < 4; ++r) {
            const float* bbp = bbox + (size_t)(bb + q * 4 + r) * 124;
            xold[r] = bbp[120 + col] - bbp[116 + col];
            ofs[r]  = bbp[120 + col];
            cs[r]   = 0.f;
            G.xdec[q * 4 + r][col] = (half_t)xold[r];
        }
    }
    __syncthreads();   // xdec visible

    // =================== decoder: 20 steps + lin + cumsum ==================
    for (int tt = 0; tt < 20; ++tt) {
        const int p = tt & 1;   // (30+tt)&1 == tt&1
        const half8 a0 = *(const half8*)&G.hbuf[p][col][q * 8];
        const half8 a1 = *(const half8*)&G.hbuf[p][col][32 + q * 8];
        const half8 a2 = *(const half8*)&G.xdec[col][q * 8];

        f32x4 Cr  = {dbr, dbr, dbr, dbr};
        f32x4 Cz  = {dbz, dbz, dbz, dbz};
        f32x4 Cnh = {dbnh, dbnh, dbnh, dbnh};
        f32x4 Cnx = {dbni, dbni, dbni, dbni};
        Cr  = MFMA16(a0, dBr0, Cr);  Cr  = MFMA16(a1, dBr1, Cr);  Cr = MFMA16(a2, dBrx, Cr);
        Cz  = MFMA16(a0, dBz0, Cz);  Cz  = MFMA16(a1, dBz1, Cz);  Cz = MFMA16(a2, dBzx, Cz);
        Cnh = MFMA16(a0, dBn0, Cnh); Cnh = MFMA16(a1, dBn1, Cnh);
        Cnx = MFMA16(a2, dBnx, Cnx);

        #pragma unroll
        for (int r = 0; r < 4; ++r) {
            const float rr = sigmoid_f(Cr[r]);
            const float zz = sigmoid_f(Cz[r]);
            const float nn = tanh_f(Cnx[r] + rr * Cnh[r]);
            hold[r] = fmaf(zz, hold[r] - nn, nn);
            G.hbuf[p ^ 1][q * 4 + r][urow] = (half_t)hold[r];
        }
        __syncthreads();   // (A) h_new visible for lin-head A-frags

        const half8 al0 = *(const half8*)&G.hbuf[p ^ 1][col][q * 8];
        const half8 al1 = *(const half8*)&G.hbuf[p ^ 1][col][32 + q * 8];
        f32x4 X = {0.f, 0.f, 0.f, 0.f};
        X = MFMA16(al0, Bl0, X);
        X = MFMA16(al1, Bl1, X);

        if (w == 0 && col < 4) {
            #pragma unroll
            for (int r = 0; r < 4; ++r) {
                const float xv = X[r] + lb + xold[r];
                xold[r] = xv;
                cs[r] += xv;
                G.xdec[q * 4 + r][col] = (half_t)xv;
                out[(size_t)(bb + q * 4 + r) * 80 + tt * 4 + col] = cs[r] + ofs[r];
            }
        }
        __syncthreads();   // (B) xdec visible for next step's gi
    }
}

// ---------------------------------------------------------------------------
extern "C" void kernel_launch(void* const* d_in, const int* in_sizes, int n_in,
                              void* d_out, int out_size, void* d_ws, size_t ws_size,
                              hipStream_t stream) {
    (void)in_sizes; (void)n_in; (void)out_size; (void)ws_size;
    const float* bbox = (const float*)d_in[0];
    const float* head = (const float*)d_in[1];
    const float* c1w  = (const float*)d_in[2];
    const float* c1b  = (const float*)d_in[3];
    const float* c2w  = (const float*)d_in[4];
    const float* c2b  = (const float*)d_in[5];
    const float* fcw  = (const float*)d_in[6];
    const float* fcb  = (const float*)d_in[7];
    const float* ewih = (const float*)d_in[8];
    const float* ewhh = (const float*)d_in[9];
    const float* ebih = (const float*)d_in[10];
    const float* ebhh = (const float*)d_in[11];
    const float* dwih = (const float*)d_in[12];
    const float* dwhh = (const float*)d_in[13];
    const float* dbih = (const float*)d_in[14];
    const float* dbhh = (const float*)d_in[15];
    const float* linw = (const float*)d_in[16];
    const float* linb = (const float*)d_in[17];
    float* out = (float*)d_out;

    float*    enc_in = (float*)d_ws;                       // 1024*30*9 floats
    unsigned* flags  = (unsigned*)((char*)d_ws + (size_t)B_ * L_ * 9 * sizeof(float));

    // zero 7680 per-conv-block flags each replay (captured in the graph)
    hipMemsetAsync(flags, 0, (B_ * L_ / 4) * sizeof(unsigned), stream);

    const int grid = NGRUBLK + (B_ * L_) / 4;              // 64 gru + 7680 conv
    fused_kernel<<<grid, 256, 0, stream>>>(bbox, head, c1w, c1b, c2w, c2b,
                                           fcw, fcb, ewih, ewhh, ebih, ebhh,
                                           dwih, dwhh, dbih, dbhh, linw, linb,
                                           enc_in, flags, out);
}

// Round 7
// 273.629 us; speedup vs baseline: 1.1322x; 1.0143x over previous
//
#include <hip/hip_runtime.h>
#include <hip/hip_bf16.h>

// ---------------------------------------------------------------------------
// Fused pipeline (R16): conv in PACKED F16 (v_pk_fma_f16), GRU unchanged.
//   R12/R14/R15 established: conv VALU-issue time (~95us busy) is conserved
//   under all scheduling changes; MFMA-at-16x16 trades VALU for latency stalls.
//   R16 halves the FMA stream instead: <2 x half> is a legal gfx9+ register
//   type; ext-vector _Float16 ops lower to v_pk_fma_f16 / v_pk_max_f16.
//   - pack across the horizontal pool pair: conv1 36->18 ops/output,
//     conv2 144->72; pairs (h[k],h[k+1]) = 2 LDS dwords + 1 v_alignbit.
//   - conv2 ic-outer with persistent accT/accB[6]: pooling folds into conv.
//   - image staged once as f16; LDS/block 38.9 -> ~22.6 KB (7 blocks/CU).
// Overlap scheme unchanged (R12): per-conv-block flags, relaxed agent-scope
// ops only, zero atomics, timestep-major conv ordering.
// ---------------------------------------------------------------------------

#define B_      1024
#define L_      30
#define H_      64
#define NGRUBLK 64

typedef _Float16 half_t;
typedef __attribute__((ext_vector_type(2))) _Float16 h2;
typedef __attribute__((ext_vector_type(4))) _Float16 h4;
typedef __attribute__((ext_vector_type(8))) _Float16 half8;
typedef __attribute__((ext_vector_type(4))) float f32x4;

#define MFMA16(A, B, C) __builtin_amdgcn_mfma_f32_16x16x32_f16(A, B, C, 0, 0, 0)

__device__ __forceinline__ float sigmoid_f(float v) {
    return __builtin_amdgcn_rcpf(1.f + __expf(-v));
}
__device__ __forceinline__ float tanh_f(float v) {
    v = fminf(fmaxf(v, -15.f), 15.f);
    const float e = __expf(2.f * v);
    return (e - 1.f) * __builtin_amdgcn_rcpf(e + 1.f);
}

// packed helpers ------------------------------------------------------------
__device__ __forceinline__ h2 pkfma(h2 a, h2 b, h2 c) {
    return __builtin_elementwise_fma(a, b, c);
}
__device__ __forceinline__ h2 pkmax(h2 a, h2 b) {
    return __builtin_elementwise_max(a, b);
}
union HU { h2 h; unsigned u; };
__device__ __forceinline__ h2 midpair(h2 lo, h2 hi) {   // (lo.hi, hi.lo)
    HU a, b, r; a.h = lo; b.h = hi;
    r.u = __builtin_amdgcn_alignbit(b.u, a.u, 16);
    return r.h;
}
struct Row { h2 p0, p12, p23; };   // pairs (h0,h1),(h1,h2),(h2,h3)

// conv sub-image LDS: 2048 + 1920 + 1440 + 240 = 5648 B
struct alignas(16) ConvSub {
    half_t s_imgh[32 * 32];      // f16 image, row stride 32 halves (64 B)
    half_t s_p1h[4][15][16];     // conv1 pooled, [ic][y][x], stride 32 B
    float  s_p2[360];            // pooled conv2 (fc layout c*36+y*6+x)
    float  s_red[60];
};

union alignas(16) SharedU {
    struct {
        half_t hbuf[2][16][72];   // [parity][batch][unit], rows padded 64->72
        half_t xenc[16][40];      // current-step x, cols 0..8 live, rest zero
        half_t xdec[16][40];      // decoder x,    cols 0..3 live, rest zero
    } g;
    ConvSub c[4];
};

__global__ __launch_bounds__(256, 4) void fused_kernel(
    const float* __restrict__ bbox,
    const float* __restrict__ head,
    const float* __restrict__ c1w, const float* __restrict__ c1b,
    const float* __restrict__ c2w, const float* __restrict__ c2b,
    const float* __restrict__ fcw, const float* __restrict__ fcb,
    const float* __restrict__ ewih, const float* __restrict__ ewhh,
    const float* __restrict__ ebih, const float* __restrict__ ebhh,
    const float* __restrict__ dwih, const float* __restrict__ dwhh,
    const float* __restrict__ dbih, const float* __restrict__ dbhh,
    const float* __restrict__ linw, const float* __restrict__ linb,
    float* __restrict__ enc_in,     // [1024][30][9] in d_ws
    unsigned*            flags,     // [7680] in d_ws, pre-zeroed via memset
    float* __restrict__ out)        // [1024][20][4]
{
    __shared__ SharedU su;
    const int tid = threadIdx.x;

    if (blockIdx.x >= NGRUBLK) {
        // ===================== conv role (4 images / block) =================
        const int cb   = (int)blockIdx.x - NGRUBLK;   // conv block 0..7679
        const int sub  = tid >> 6;
        const int lane = tid & 63;
        const int img  = (cb << 2) | sub;
        const int ts   = img >> 10;       // timestep-major ordering
        const int b    = img & 1023;
        auto& S = su.c[sub];

        // ---- stage image as f16 -------------------------------------------
        {
            const float4* src = (const float4*)(head + ((size_t)b * 31 + (size_t)ts) * 1024);
            #pragma unroll
            for (int i = 0; i < 4; ++i) {
                const float4 v = src[lane + 64 * i];
                h4 hv;
                hv[0] = (half_t)v.x; hv[1] = (half_t)v.y;
                hv[2] = (half_t)v.z; hv[3] = (half_t)v.w;
                *(h4*)&S.s_imgh[4 * (lane + 64 * i)] = hv;
            }
        }
        __syncthreads();

        const h2 z2 = (h2)(half_t)0.f;

        // ---- conv1 + pool, packed over the horizontal pool pair -----------
        if (lane < 60) {
            const int c = lane / 15, px = lane % 15;
            h2 wp[9];
            #pragma unroll
            for (int k = 0; k < 9; ++k) {
                const half_t wv = (half_t)c1w[c * 9 + k];
                wp[k] = (h2){wv, wv};
            }
            const half_t bh = (half_t)c1b[c];
            const h2 bb2 = (h2){bh, bh};

            auto load_row = [&](int y) -> Row {
                const h2* rp = (const h2*)&S.s_imgh[y * 32 + 2 * px];
                Row r; r.p0 = rp[0]; r.p23 = rp[1]; r.p12 = midpair(r.p0, r.p23);
                return r;
            };
            auto c1out = [&](const Row& A, const Row& B, const Row& C, const Row& D) -> half_t {
                h2 t = bb2, u = bb2;
                t = pkfma(wp[0], A.p0, t); t = pkfma(wp[1], A.p12, t); t = pkfma(wp[2], A.p23, t);
                t = pkfma(wp[3], B.p0, t); t = pkfma(wp[4], B.p12, t); t = pkfma(wp[5], B.p23, t);
                t = pkfma(wp[6], C.p0, t); t = pkfma(wp[7], C.p12, t); t = pkfma(wp[8], C.p23, t);
                u = pkfma(wp[0], B.p0, u); u = pkfma(wp[1], B.p12, u); u = pkfma(wp[2], B.p23, u);
                u = pkfma(wp[3], C.p0, u); u = pkfma(wp[4], C.p12, u); u = pkfma(wp[5], C.p23, u);
                u = pkfma(wp[6], D.p0, u); u = pkfma(wp[7], D.p12, u); u = pkfma(wp[8], D.p23, u);
                const h2 m = pkmax(pkmax(t, u), z2);   // relu folded (monotone)
                return m[0] >= m[1] ? m[0] : m[1];
            };

            Row r[6];
            r[0] = load_row(0); r[1] = load_row(1);
            #pragma unroll
            for (int i = 0; i < 7; ++i) {
                const int s0 = (4 * i) % 6, s1 = (4 * i + 1) % 6, s2 = (4 * i + 2) % 6;
                const int s3 = (4 * i + 3) % 6, s4 = (4 * i + 4) % 6, s5 = (4 * i + 5) % 6;
                r[s2] = load_row(4 * i + 2);
                r[s3] = load_row(4 * i + 3);
                S.s_p1h[c][2 * i][px] = c1out(r[s0], r[s1], r[s2], r[s3]);
                r[s4] = load_row(4 * i + 4);
                r[s5] = load_row(4 * i + 5);
                S.s_p1h[c][2 * i + 1][px] = c1out(r[s2], r[s3], r[s4], r[s5]);
            }
            r[0] = load_row(30); r[1] = load_row(31);
            S.s_p1h[c][14][px] = c1out(r[4], r[5], r[0], r[1]);
        }
        __syncthreads();

        // ---- conv2 + pool, packed; ic-outer with persistent accumulators --
        if (lane < 60) {
            const int c = lane / 6, x = lane % 6;
            const half_t b2h = (half_t)c2b[c];
            const h2 b22 = (h2){b2h, b2h};
            h2 accT[6], accB[6];
            #pragma unroll
            for (int y = 0; y < 6; ++y) { accT[y] = b22; accB[y] = z2; }

            #pragma unroll
            for (int ic = 0; ic < 4; ++ic) {
                h2 wp[9];
                #pragma unroll
                for (int k = 0; k < 9; ++k) {
                    const half_t wv = (half_t)c2w[(c * 4 + ic) * 9 + k];
                    wp[k] = (h2){wv, wv};
                }
                auto load_row = [&](int row) -> Row {
                    const h2* rp = (const h2*)&S.s_p1h[ic][row][2 * x];
                    Row r; r.p0 = rp[0]; r.p23 = rp[1]; r.p12 = midpair(r.p0, r.p23);
                    return r;
                };
                auto acc = [&](int y, const Row& A, const Row& B, const Row& C, const Row& D) {
                    h2 t = accT[y], u = accB[y];
                    t = pkfma(wp[0], A.p0, t); t = pkfma(wp[1], A.p12, t); t = pkfma(wp[2], A.p23, t);
                    t = pkfma(wp[3], B.p0, t); t = pkfma(wp[4], B.p12, t); t = pkfma(wp[5], B.p23, t);
                    t = pkfma(wp[6], C.p0, t); t = pkfma(wp[7], C.p12, t); t = pkfma(wp[8], C.p23, t);
                    u = pkfma(wp[0], B.p0, u); u = pkfma(wp[1], B.p12, u); u = pkfma(wp[2], B.p23, u);
                    u = pkfma(wp[3], C.p0, u); u = pkfma(wp[4], C.p12, u); u = pkfma(wp[5], C.p23, u);
                    u = pkfma(wp[6], D.p0, u); u = pkfma(wp[7], D.p12, u); u = pkfma(wp[8], D.p23, u);
                    accT[y] = t; accB[y] = u;
                };

                Row R[6];
                R[0] = load_row(0); R[1] = load_row(1);
                #pragma unroll
                for (int i = 0; i < 3; ++i) {
                    const int s0 = (4 * i) % 6, s1 = (4 * i + 1) % 6, s2 = (4 * i + 2) % 6;
                    const int s3 = (4 * i + 3) % 6, s4 = (4 * i + 4) % 6, s5 = (4 * i + 5) % 6;
                    R[s2] = load_row(4 * i + 2);
                    R[s3] = load_row(4 * i + 3);
                    acc(2 * i, R[s0], R[s1], R[s2], R[s3]);
                    R[s4] = load_row(4 * i + 4);
                    R[s5] = load_row(4 * i + 5);
                    acc(2 * i + 1, R[s2], R[s3], R[s4], R[s5]);
                }
            }
            #pragma unroll
            for (int y = 0; y < 6; ++y) {
                const h2 m = pkmax(pkmax(accT[y], accB[y]), z2);  // relu+pool
                S.s_p2[c * 36 + y * 6 + x] = fmaxf((float)m[0], (float)m[1]);
            }
        }
        __syncthreads();

        // ---- fc partials (unchanged, f32) ---------------------------------
        if (lane < 60) {
            const int o = lane / 12, i0 = lane % 12;
            const float* wrow = fcw + o * 360;
            float acc = 0.f;
            #pragma unroll
            for (int k = 0; k < 30; ++k) {
                const int i = i0 + 12 * k;
                acc = fmaf(wrow[i], S.s_p2[i], acc);
            }
            S.s_red[lane] = acc;
        }
        __syncthreads();

        // publish via agent-scope RELAXED stores (bypass non-coherent caches)
        float* dst = enc_in + ((size_t)b * L_ + ts) * 9;
        if (lane < 5) {
            float acc = fcb[lane];
            #pragma unroll
            for (int k = 0; k < 12; ++k) acc += S.s_red[lane * 12 + k];
            __hip_atomic_store(&dst[4 + lane], acc, __ATOMIC_RELAXED, __HIP_MEMORY_SCOPE_AGENT);
        } else if (lane >= 8 && lane < 12) {
            const int d = lane - 8;
            const float* bbp = bbox + (size_t)b * 124 + (size_t)ts * 4;
            __hip_atomic_store(&dst[d], bbp[4 + d] - bbp[d], __ATOMIC_RELAXED, __HIP_MEMORY_SCOPE_AGENT);
        }
        __syncthreads();   // drains vmcnt -> all 4 sub-images' stores complete
        if (tid == 0)
            __hip_atomic_store(&flags[cb], 1u, __ATOMIC_RELAXED, __HIP_MEMORY_SCOPE_AGENT);
        return;
    }

    // ======================= GRU role (blocks 0..63) ========================
    const int g   = (int)blockIdx.x;        // GRU block id
    const int bb  = g * 16;                 // first batch of this block
    const int w   = tid >> 6;               // wave 0..3
    const int l   = tid & 63;
    const int q   = l >> 4;                 // quad 0..3
    const int col = l & 15;
    auto& G = su.g;

    // ---- zero LDS (7168 B = 448 int4) --------------------------------------
    {
        int4* p = (int4*)&G;
        #pragma unroll
        for (int i = 0; i < 2; ++i) {
            const int idx = tid + 256 * i;
            if (idx < (int)(sizeof(G) / 16)) p[idx] = int4{0, 0, 0, 0};
        }
    }

    // ---- weight B-fragments (register-resident, f16) -----------------------
    const int urow = 16 * w + col;
    auto whh_frag = [&](const float* W, int gate, int kap) -> half8 {
        const float* rp = W + (size_t)(gate * 64 + urow) * 64 + kap * 32 + q * 8;
        half8 f;
        #pragma unroll
        for (int j = 0; j < 8; ++j) f[j] = (half_t)rp[j];
        return f;
    };
    auto wih_frag = [&](const float* W, int gate, int indim) -> half8 {
        half8 f;
        #pragma unroll
        for (int j = 0; j < 8; ++j) {
            const int d = q * 8 + j;
            f[j] = (d < indim) ? (half_t)W[(size_t)(gate * 64 + urow) * indim + d]
                               : (half_t)0.f;
        }
        return f;
    };

    // encoder frags only (decoder frags loaded after the encoder loop)
    const half8 eBr0 = whh_frag(ewhh, 0, 0), eBr1 = whh_frag(ewhh, 0, 1);
    const half8 eBz0 = whh_frag(ewhh, 1, 0), eBz1 = whh_frag(ewhh, 1, 1);
    const half8 eBn0 = whh_frag(ewhh, 2, 0), eBn1 = whh_frag(ewhh, 2, 1);
    const half8 eBrx = wih_frag(ewih, 0, 9);
    const half8 eBzx = wih_frag(ewih, 1, 9);
    const half8 eBnx = wih_frag(ewih, 2, 9);

    const float ebr  = ebih[urow]       + ebhh[urow];
    const float ebz  = ebih[64 + urow]  + ebhh[64 + urow];
    const float ebnh = ebhh[128 + urow];
    const float ebni = ebih[128 + urow];

    float hold[4] = {0.f, 0.f, 0.f, 0.f};
    __syncthreads();   // LDS zeros visible

    // =================== encoder: 30 steps, paced by conv ==================
    for (int t = 0; t < L_; ++t) {
        // wait only for the 4 conv blocks that produce batches bb..bb+15 at t
        if (tid < 4) {
            const unsigned fidx = (unsigned)(t * 256 + 4 * g + tid);
            while (__hip_atomic_load(&flags[fidx], __ATOMIC_RELAXED,
                                     __HIP_MEMORY_SCOPE_AGENT) == 0u)
                __builtin_amdgcn_s_sleep(2);
        }
        __syncthreads();
        if (tid < 144) {   // stage 16 batches x 9 dims for this step
            const int bq = tid / 9, d = tid - 9 * bq;
            const float v = __hip_atomic_load(
                &enc_in[((size_t)(bb + bq) * L_ + t) * 9 + d],
                __ATOMIC_RELAXED, __HIP_MEMORY_SCOPE_AGENT);
            G.xenc[bq][d] = (half_t)v;
        }
        __syncthreads();

        const int p = t & 1;
        const half8 a0 = *(const half8*)&G.hbuf[p][col][q * 8];        // k 0..31
        const half8 a1 = *(const half8*)&G.hbuf[p][col][32 + q * 8];   // k 32..63
        const half8 a2 = *(const half8*)&G.xenc[col][q * 8];           // k 64..95

        f32x4 Cr  = {ebr, ebr, ebr, ebr};
        f32x4 Cz  = {ebz, ebz, ebz, ebz};
        f32x4 Cnh = {ebnh, ebnh, ebnh, ebnh};
        f32x4 Cnx = {ebni, ebni, ebni, ebni};
        Cr  = MFMA16(a0, eBr0, Cr);  Cr  = MFMA16(a1, eBr1, Cr);  Cr = MFMA16(a2, eBrx, Cr);
        Cz  = MFMA16(a0, eBz0, Cz);  Cz  = MFMA16(a1, eBz1, Cz);  Cz = MFMA16(a2, eBzx, Cz);
        Cnh = MFMA16(a0, eBn0, Cnh); Cnh = MFMA16(a1, eBn1, Cnh);
        Cnx = MFMA16(a2, eBnx, Cnx);

        #pragma unroll
        for (int r = 0; r < 4; ++r) {
            const float rr = sigmoid_f(Cr[r]);
            const float zz = sigmoid_f(Cz[r]);
            const float nn = tanh_f(Cnx[r] + rr * Cnh[r]);
            hold[r] = fmaf(zz, hold[r] - nn, nn);
            G.hbuf[p ^ 1][q * 4 + r][urow] = (half_t)hold[r];
        }
        __syncthreads();
    }

    // ---- decoder weights / lin head / x0 (loaded after encoder) ------------
    const half8 dBr0 = whh_frag(dwhh, 0, 0), dBr1 = whh_frag(dwhh, 0, 1);
    const half8 dBz0 = whh_frag(dwhh, 1, 0), dBz1 = whh_frag(dwhh, 1, 1);
    const half8 dBn0 = whh_frag(dwhh, 2, 0), dBn1 = whh_frag(dwhh, 2, 1);
    const half8 dBrx = wih_frag(dwih, 0, 4);
    const half8 dBzx = wih_frag(dwih, 1, 4);
    const half8 dBnx = wih_frag(dwih, 2, 4);

    half8 Bl0, Bl1;
    #pragma unroll
    for (int j = 0; j < 8; ++j) {
        Bl0[j] = (col < 4) ? (half_t)linw[col * 64 +      q * 8 + j] : (half_t)0.f;
        Bl1[j] = (col < 4) ? (half_t)linw[col * 64 + 32 + q * 8 + j] : (half_t)0.f;
    }

    const float dbr  = dbih[urow]       + dbhh[urow];
    const float dbz  = dbih[64 + urow]  + dbhh[64 + urow];
    const float dbnh = dbhh[128 + urow];
    const float dbni = dbih[128 + urow];
    const float lb   = (col < 4) ? linb[col] : 0.f;

    float xold[4], ofs[4], cs[4];
    if (w == 0 && col < 4) {
        #pragma unroll
        for (int r = 0; r < 4; ++r) {
            const float* bbp = bbox + (size_t)(bb + q * 4 + r) * 124;
            xold[r] = bbp[120 + col] - bbp[116 + col];
            ofs[r]  = bbp[120 + col];
            cs[r]   = 0.f;
            G.xdec[q * 4 + r][col] = (half_t)xold[r];
        }
    }
    __syncthreads();   // xdec visible

    // =================== decoder: 20 steps + lin + cumsum ==================
    for (int tt = 0; tt < 20; ++tt) {
        const int p = tt & 1;   // (30+tt)&1 == tt&1
        const half8 a0 = *(const half8*)&G.hbuf[p][col][q * 8];
        const half8 a1 = *(const half8*)&G.hbuf[p][col][32 + q * 8];
        const half8 a2 = *(const half8*)&G.xdec[col][q * 8];

        f32x4 Cr  = {dbr, dbr, dbr, dbr};
        f32x4 Cz  = {dbz, dbz, dbz, dbz};
        f32x4 Cnh = {dbnh, dbnh, dbnh, dbnh};
        f32x4 Cnx = {dbni, dbni, dbni, dbni};
        Cr  = MFMA16(a0, dBr0, Cr);  Cr  = MFMA16(a1, dBr1, Cr);  Cr = MFMA16(a2, dBrx, Cr);
        Cz  = MFMA16(a0, dBz0, Cz);  Cz  = MFMA16(a1, dBz1, Cz);  Cz = MFMA16(a2, dBzx, Cz);
        Cnh = MFMA16(a0, dBn0, Cnh); Cnh = MFMA16(a1, dBn1, Cnh);
        Cnx = MFMA16(a2, dBnx, Cnx);

        #pragma unroll
        for (int r = 0; r < 4; ++r) {
            const float rr = sigmoid_f(Cr[r]);
            const float zz = sigmoid_f(Cz[r]);
            const float nn = tanh_f(Cnx[r] + rr * Cnh[r]);
            hold[r] = fmaf(zz, hold[r] - nn, nn);
            G.hbuf[p ^ 1][q * 4 + r][urow] = (half_t)hold[r];
        }
        __syncthreads();   // (A) h_new visible for lin-head A-frags

        const half8 al0 = *(const half8*)&G.hbuf[p ^ 1][col][q * 8];
        const half8 al1 = *(const half8*)&G.hbuf[p ^ 1][col][32 + q * 8];
        f32x4 X = {0.f, 0.f, 0.f, 0.f};
        X = MFMA16(al0, Bl0, X);
        X = MFMA16(al1, Bl1, X);

        if (w == 0 && col < 4) {
            #pragma unroll
            for (int r = 0; r < 4; ++r) {
                const float xv = X[r] + lb + xold[r];
                xold[r] = xv;
                cs[r] += xv;
                G.xdec[q * 4 + r][col] = (half_t)xv;
                out[(size_t)(bb + q * 4 + r) * 80 + tt * 4 + col] = cs[r] + ofs[r];
            }
        }
        __syncthreads();   // (B) xdec visible for next step's gi
    }
}

// ---------------------------------------------------------------------------
extern "C" void kernel_launch(void* const* d_in, const int* in_sizes, int n_in,
                              void* d_out, int out_size, void* d_ws, size_t ws_size,
                              hipStream_t stream) {
    (void)in_sizes; (void)n_in; (void)out_size; (void)ws_size;
    const float* bbox = (const float*)d_in[0];
    const float* head = (const float*)d_in[1];
    const float* c1w  = (const float*)d_in[2];
    const float* c1b  = (const float*)d_in[3];
    const float* c2w  = (const float*)d_in[4];
    const float* c2b  = (const float*)d_in[5];
    const float* fcw  = (const float*)d_in[6];
    const float* fcb  = (const float*)d_in[7];
    const float* ewih = (const float*)d_in[8];
    const float* ewhh = (const float*)d_in[9];
    const float* ebih = (const float*)d_in[10];
    const float* ebhh = (const float*)d_in[11];
    const float* dwih = (const float*)d_in[12];
    const float* dwhh = (const float*)d_in[13];
    const float* dbih = (const float*)d_in[14];
    const float* dbhh = (const float*)d_in[15];
    const float* linw = (const float*)d_in[16];
    const float* linb = (const float*)d_in[17];
    float* out = (float*)d_out;

    float*    enc_in = (float*)d_ws;                       // 1024*30*9 floats
    unsigned* flags  = (unsigned*)((char*)d_ws + (size_t)B_ * L_ * 9 * sizeof(float));

    // zero 7680 per-conv-block flags each replay (captured in the graph)
    hipMemsetAsync(flags, 0, (B_ * L_ / 4) * sizeof(unsigned), stream);

    const int grid = NGRUBLK + (B_ * L_) / 4;              // 64 gru + 7680 conv
    fused_kernel<<<grid, 256, 0, stream>>>(bbox, head, c1w, c1b, c2w, c2b,
                                           fcw, fcb, ewih, ewhh, ebih, ebhh,
                                           dwih, dwhh, dbih, dbhh, linw, linb,
                                           enc_in, flags, out);
}